// Round 5
// baseline (216.754 us; speedup 1.0000x reference)
//
#include <hip/hip_runtime.h>

// ---------------------------------------------------------------------------
// MultiHeadAttention forward, MI355X (gfx950), bf16 MFMA pipeline.
// Round 5:
//   attn: barrier-free. K/V read direct global->reg (L2-resident; FETCH was
//         12MB). V in contiguous 64x64 tiles. 2-wave blocks (kv-split pair),
//         2048 blocks, LPT strip order, setprio around MFMA.
//   gemm: BK=64 (half the barriers) + row-XOR LDS swizzle (8-way read
//         conflict -> ~2-way), pre-swizzled global_load_lds source.
// ---------------------------------------------------------------------------

typedef __attribute__((ext_vector_type(8))) short bf16x8;
typedef __attribute__((ext_vector_type(4))) float f32x4;
typedef __attribute__((ext_vector_type(16))) float f32x16;

#define S_LEN 4096
#define DM 1024
#define NH 16
#define DH 64

static __device__ __forceinline__ unsigned short f2bf(float f) {
  union { float f; unsigned u; } x; x.f = f;
  unsigned u = x.u;
  u += 0x7fffu + ((u >> 16) & 1u);   // round-to-nearest-even
  return (unsigned short)(u >> 16);
}

// pack two f32 -> one u32 of two bf16 (RNE), single HW instr on gfx950
static __device__ __forceinline__ unsigned pk2(float lo, float hi) {
  unsigned r;
  asm("v_cvt_pk_bf16_f32 %0, %1, %2" : "=v"(r) : "v"(lo), "v"(hi));
  return r;
}

static __device__ __forceinline__ float exp2_(float x) {
#if __has_builtin(__builtin_amdgcn_exp2f)
  return __builtin_amdgcn_exp2f(x);
#else
  return exp2f(x);
#endif
}

#define GLL16(gsrc, ldst)                                                      \
  __builtin_amdgcn_global_load_lds(                                            \
      (const __attribute__((address_space(1))) void*)(gsrc),                   \
      (__attribute__((address_space(3))) void*)(ldst), 16, 0, 0)

// ---------------------------------------------------------------- cast kernel
struct CastArgs {
  const float* src[8];
  unsigned short* dst[8];
  int n[8];
  float scl[8];
};

__global__ __launch_bounds__(256) void cast_all(CastArgs a) {
  int which = blockIdx.y;
  const float* __restrict__ src = a.src[which];
  unsigned short* __restrict__ dst = a.dst[which];
  int n = a.n[which];
  float s = a.scl[which];
  int i = (blockIdx.x * 256 + threadIdx.x) * 8;
  if (i >= n) return;
  f32x4 v0 = *(const f32x4*)(src + i);
  f32x4 v1 = *(const f32x4*)(src + i + 4);
  union { bf16x8 v; unsigned short u[8]; } o;
#pragma unroll
  for (int j = 0; j < 4; j++) { o.u[j] = f2bf(v0[j] * s); o.u[4 + j] = f2bf(v1[j] * s); }
  *(bf16x8*)(dst + i) = o.v;
}

// ---------------------------------------------------------------- GEMM body
// C[4096][1024] = A[4096][1024] @ B[1024][1024]^T  (bf16; B is N x K)
// 128x128 tile, BK=64, 4 waves x 64x64. LDS tiles [128][64] shorts with
// row-XOR swizzle: element (row, c) lives at row*64 + (c ^ ((row&7)<<3)).
// Staged via global_load_lds with pre-swizzled GLOBAL source (linear LDS dst).
// mode 0: fp32 C[s][n]; mode 1: bf16 (h,s,d); mode 2: bf16 V-tiles
// [h][s/64][d][s%64] (contiguous 8KB per 64-kv tile).
static __device__ __forceinline__ void gemm_body(
    const unsigned short* __restrict__ A, const unsigned short* __restrict__ B,
    void* __restrict__ Cout, int mode, unsigned short* As, unsigned short* Bs) {
  const int K = 1024;
  int tid = threadIdx.x;
  int wid = tid >> 6, lane = tid & 63;
  int m0 = blockIdx.y * 128, n0 = blockIdx.x * 128;
  int wr = (wid >> 1) * 64, wc = (wid & 1) * 64;
  int g = lane >> 4, r = lane & 15;

  // staging: round rr covers rows rr*32 + wid*8 + (lane>>3), cols: lane&7
  // pre-swizzled source column (shorts): 8*((lane&7) ^ ((lane>>3)&7))
  const int srow = wid * 8 + (lane >> 3);
  const int scol = 8 * ((lane & 7) ^ ((lane >> 3) & 7));
  const unsigned short* gA[4];
  const unsigned short* gB[4];
#pragma unroll
  for (int rr = 0; rr < 4; rr++) {
    gA[rr] = A + (size_t)(m0 + rr * 32 + srow) * K + scol;
    gB[rr] = B + (size_t)(n0 + rr * 32 + srow) * K + scol;
  }

  f32x4 acc[4][4] = {};
  const int rsw = (r & 7) << 3;   // read-side swizzle (shorts)

  for (int k0 = 0; k0 < K; k0 += 64) {
#pragma unroll
    for (int rr = 0; rr < 4; rr++) {
      GLL16(gA[rr] + k0, As + wid * 512 + rr * 2048);
      GLL16(gB[rr] + k0, Bs + wid * 512 + rr * 2048);
    }
    __syncthreads();

#pragma unroll
    for (int kk = 0; kk < 64; kk += 32) {
      bf16x8 af[4], bfr[4];
#pragma unroll
      for (int mi = 0; mi < 4; mi++)
        af[mi] = *(const bf16x8*)&As[(wr + mi * 16 + r) * 64 + ((kk + g * 8) ^ rsw)];
#pragma unroll
      for (int ni = 0; ni < 4; ni++)
        bfr[ni] = *(const bf16x8*)&Bs[(wc + ni * 16 + r) * 64 + ((kk + g * 8) ^ rsw)];
#pragma unroll
      for (int mi = 0; mi < 4; mi++)
#pragma unroll
        for (int ni = 0; ni < 4; ni++)
          acc[mi][ni] = __builtin_amdgcn_mfma_f32_16x16x32_bf16(
              af[mi], bfr[ni], acc[mi][ni], 0, 0, 0);
    }
    __syncthreads();
  }

  // epilogue: C frag layout col = lane&15, row = (lane>>4)*4 + reg
  if (mode == 0) {
    float* C = (float*)Cout;
#pragma unroll
    for (int mi = 0; mi < 4; mi++) {
      int row = m0 + wr + mi * 16 + g * 4;
#pragma unroll
      for (int ni = 0; ni < 4; ni++) {
        int c = n0 + wc + ni * 16 + r;
#pragma unroll
        for (int j = 0; j < 4; j++)
          C[(size_t)(row + j) * DM + c] = acc[mi][ni][j];
      }
    }
  } else if (mode == 1) {
    unsigned short* Cb = (unsigned short*)Cout;
#pragma unroll
    for (int mi = 0; mi < 4; mi++) {
      int row = m0 + wr + mi * 16 + g * 4;
#pragma unroll
      for (int ni = 0; ni < 4; ni++) {
        int c = n0 + wc + ni * 16 + r;
        int h = c >> 6, d = c & 63;
#pragma unroll
        for (int j = 0; j < 4; j++)
          Cb[(size_t)h * (S_LEN * DH) + (size_t)(row + j) * DH + d] =
              f2bf(acc[mi][ni][j]);
      }
    }
  } else {
    // V tiles: [h][s/64][d][s%64]
    unsigned short* Cb = (unsigned short*)Cout;
#pragma unroll
    for (int mi = 0; mi < 4; mi++) {
      int row = m0 + wr + mi * 16 + g * 4;
#pragma unroll
      for (int ni = 0; ni < 4; ni++) {
        int c = n0 + wc + ni * 16 + r;
        int h = c >> 6, d = c & 63;
#pragma unroll
        for (int j = 0; j < 4; j++) {
          int s = row + j;
          Cb[(size_t)h * (S_LEN * DH) + (size_t)(s >> 6) * 4096 + d * 64 + (s & 63)] =
              f2bf(acc[mi][ni][j]);
        }
      }
    }
  }
}

struct ProjArgs {
  const unsigned short* A[3];
  const unsigned short* B[3];
  unsigned short* C[3];
  int mode[3];
};

__global__ __launch_bounds__(256, 2) void gemm_proj(ProjArgs p) {
  __shared__ unsigned short As[8192];
  __shared__ unsigned short Bs[8192];
  int z = blockIdx.z;
  gemm_body(p.A[z], p.B[z], p.C[z], p.mode[z], As, Bs);
}

__global__ __launch_bounds__(256, 2) void gemm_one(
    const unsigned short* __restrict__ A, const unsigned short* __restrict__ B,
    void* __restrict__ Cout, int mode) {
  __shared__ unsigned short As[8192];
  __shared__ unsigned short Bs[8192];
  gemm_body(A, B, Cout, mode, As, Bs);
}

// ---------------------------------------------------------------- attention
// 2048 blocks (128 q-strips x 16 heads) x 128 threads (2 waves = kv-halves).
// Barrier-free main loop: K/V frags read directly from global (L2-resident).
// Qh,Kh: (h,s,d); V4: [h][s/64][d][s%64] tiles. One barrier total (combine).
__global__ __launch_bounds__(128, 3) void attn_fwd(
    const unsigned short* __restrict__ Qh, const unsigned short* __restrict__ Kh,
    const unsigned short* __restrict__ V4, unsigned short* __restrict__ O) {
  __shared__ float scr[64 * 35];   // combine scratch, stride 35 (conflict-free)

  const int b = blockIdx.x;
  const int hd = b & 15;
  const int u = b >> 4;                               // 0..127
  const int strip = (u < 64) ? (127 - 2 * u) : (2 * (u - 64));  // LPT order
  const int qw = strip * 32;
  const int tid = threadIdx.x;
  const int gg = tid >> 6;             // kv half
  const int lane = tid & 63;
  const int l31 = lane & 31, hi = lane >> 5;
  const int qrow = qw + l31;

  const unsigned short* Qb = Qh + (size_t)hd * (S_LEN * DH);
  const unsigned short* Kb = Kh + (size_t)hd * (S_LEN * DH);
  const unsigned short* Vb = V4 + (size_t)hd * (S_LEN * DH);

  // Q fragments (B operand): col = q (l31), k = m*16 + hi*8 + j (pre-scaled)
  bf16x8 qf[4];
#pragma unroll
  for (int m = 0; m < 4; m++)
    qf[m] = *(const bf16x8*)&Qb[(size_t)qrow * DH + m * 16 + hi * 8];

  f32x16 oacc[2] = {};    // O^T: d = dt*32 + (rg&3)+8*(rg>>2)+4*hi, col q=l31
  float m_r = -1e30f, l_r = 0.f;

  const int nt = (strip >> 1) + 1;     // 64-kv tiles needed by this strip
  const int nh = nt >> 1;
  const int tb = gg ? nh : 0;
  const int te = gg ? nt : nh;         // gg=0 tiles are always interior

  for (int t = tb; t < te; ++t) {
    const int kv0 = t * 64;
    const bool hiP = (kv0 + 32 <= qw + 31);
    const bool diag = (kv0 + 63 > qw);
    const unsigned short* Kt = Kb + (size_t)kv0 * DH;
    const unsigned short* Vt = Vb + (size_t)t * 4096;

    // K frags first (QK waits only on these), then V (in flight thru softmax)
    bf16x8 kf0[4], kf1[4];
#pragma unroll
    for (int m = 0; m < 4; m++)
      kf0[m] = *(const bf16x8*)&Kt[l31 * DH + m * 16 + hi * 8];
#pragma unroll
    for (int m = 0; m < 4; m++)
      kf1[m] = *(const bf16x8*)&Kt[(32 + l31) * DH + m * 16 + hi * 8];
    bf16x8 vf[8];
#pragma unroll
    for (int i = 0; i < 8; i++) {
      const int dt = i >> 2, c = (i >> 1) & 1, n = i & 1;
      vf[i] = *(const bf16x8*)&Vt[(dt * 32 + l31) * 64 + c * 32 + n * 16 + hi * 8];
    }

    // ---- QK^T (swapped): S^T[kv][q]
    f32x16 s0 = {}, s1 = {};
    __builtin_amdgcn_s_setprio(1);
#pragma unroll
    for (int m = 0; m < 4; m++)
      s0 = __builtin_amdgcn_mfma_f32_32x32x16_bf16(kf0[m], qf[m], s0, 0, 0, 0);
#pragma unroll
    for (int m = 0; m < 4; m++)
      s1 = __builtin_amdgcn_mfma_f32_32x32x16_bf16(kf1[m], qf[m], s1, 0, 0, 0);
    __builtin_amdgcn_s_setprio(0);

    // ---- causal mask (diag tiles only); reg -> kv: (rg&3)+8*(rg>>2)+4*hi
    if (diag) {
#pragma unroll
      for (int rg = 0; rg < 16; rg++) {
        const int kvl = (rg & 3) + 8 * (rg >> 2) + 4 * hi;
        s0[rg] = (kv0 + kvl <= qrow) ? s0[rg] : -1e30f;
        s1[rg] = (hiP && kv0 + 32 + kvl <= qrow) ? s1[rg] : -1e30f;
      }
    }
    // ---- max: in-lane tree + shfl_xor(32) cross-half
    float a0 = fmaxf(s0[0], s0[1]),  a1 = fmaxf(s0[2], s0[3]);
    float a2 = fmaxf(s0[4], s0[5]),  a3 = fmaxf(s0[6], s0[7]);
    float a4 = fmaxf(s0[8], s0[9]),  a5 = fmaxf(s0[10], s0[11]);
    float a6 = fmaxf(s0[12], s0[13]), a7 = fmaxf(s0[14], s0[15]);
    float b0 = fmaxf(s1[0], s1[1]),  b1 = fmaxf(s1[2], s1[3]);
    float b2 = fmaxf(s1[4], s1[5]),  b3 = fmaxf(s1[6], s1[7]);
    float b4 = fmaxf(s1[8], s1[9]),  b5 = fmaxf(s1[10], s1[11]);
    float b6 = fmaxf(s1[12], s1[13]), b7 = fmaxf(s1[14], s1[15]);
    float c0 = fmaxf(fmaxf(a0, a1), fmaxf(a2, a3));
    float c1 = fmaxf(fmaxf(a4, a5), fmaxf(a6, a7));
    float c2 = fmaxf(fmaxf(b0, b1), fmaxf(b2, b3));
    float c3 = fmaxf(fmaxf(b4, b5), fmaxf(b6, b7));
    float mx = fmaxf(fmaxf(c0, c1), fmaxf(c2, c3));
    mx = fmaxf(mx, __shfl_xor(mx, 32, 64));
    // ---- defer-max (T13)
    if (__any(mx > m_r + 10.0f)) {
      float mnew = fmaxf(m_r, mx);
      float sc = exp2_(m_r - mnew);
      m_r = mnew;
      l_r *= sc;
#pragma unroll
      for (int dt = 0; dt < 2; dt++)
#pragma unroll
        for (int rg = 0; rg < 16; rg++) oacc[dt][rg] *= sc;
    }
    // ---- P = exp2(S - m)
#pragma unroll
    for (int rg = 0; rg < 16; rg++) {
      s0[rg] = exp2_(s0[rg] - m_r);
      s1[rg] = exp2_(s1[rg] - m_r);
    }
    // ---- row-sum + cross-half
    float r0 = (s0[0] + s0[1]) + (s0[2] + s0[3]);
    float r1 = (s0[4] + s0[5]) + (s0[6] + s0[7]);
    float r2 = (s0[8] + s0[9]) + (s0[10] + s0[11]);
    float r3 = (s0[12] + s0[13]) + (s0[14] + s0[15]);
    float r4 = (s1[0] + s1[1]) + (s1[2] + s1[3]);
    float r5 = (s1[4] + s1[5]) + (s1[6] + s1[7]);
    float r6 = (s1[8] + s1[9]) + (s1[10] + s1[11]);
    float r7 = (s1[12] + s1[13]) + (s1[14] + s1[15]);
    float rs = ((r0 + r1) + (r2 + r3)) + ((r4 + r5) + (r6 + r7));
    rs += __shfl_xor(rs, 32, 64);
    l_r += rs;
    // ---- P -> bf16 frags via cvt_pk + shfl_xor(32); PV: O^T += V^T x P
#pragma unroll
    for (int c = 0; c < 2; c++) {
      const f32x16 P = c ? s1 : s0;
      uint2 pk[4], pp[4];
#pragma unroll
      for (int blk = 0; blk < 4; blk++) {
        pk[blk].x = pk2(P[blk * 4 + 0], P[blk * 4 + 1]);
        pk[blk].y = pk2(P[blk * 4 + 2], P[blk * 4 + 3]);
        pp[blk].x = (unsigned)__shfl_xor((int)pk[blk].x, 32, 64);
        pp[blk].y = (unsigned)__shfl_xor((int)pk[blk].y, 32, 64);
      }
      __builtin_amdgcn_s_setprio(1);
#pragma unroll
      for (int n = 0; n < 2; n++) {
        union { unsigned w[4]; bf16x8 v; } u2;
        u2.w[0] = hi ? pp[2 * n + 1].x : pk[2 * n].x;
        u2.w[1] = hi ? pp[2 * n + 1].y : pk[2 * n].y;
        u2.w[2] = hi ? pk[2 * n + 1].x : pp[2 * n].x;
        u2.w[3] = hi ? pk[2 * n + 1].y : pp[2 * n].y;
#pragma unroll
        for (int dt = 0; dt < 2; dt++)
          oacc[dt] = __builtin_amdgcn_mfma_f32_32x32x16_bf16(
              vf[dt * 4 + c * 2 + n], u2.v, oacc[dt], 0, 0, 0);
      }
      __builtin_amdgcn_s_setprio(0);
    }
  }

  // ---- combine the two kv-halves (one barrier total)
  const int sbase = lane * 35;
  if (gg == 1) {
#pragma unroll
    for (int dt = 0; dt < 2; dt++)
#pragma unroll
      for (int rg = 0; rg < 16; rg++) scr[sbase + dt * 16 + rg] = oacc[dt][rg];
    scr[sbase + 32] = m_r;
    scr[sbase + 33] = l_r;
  }
  __syncthreads();
  if (gg == 0) {
    float mB = scr[sbase + 32], lB = scr[sbase + 33];
    float mS = fmaxf(m_r, mB);
    float sA = exp2_(m_r - mS);
    float sB = exp2_(mB - mS);
    float rl = 1.0f / (l_r * sA + lB * sB);
    float fA = sA * rl, fB = sB * rl;
#pragma unroll
    for (int dt = 0; dt < 2; dt++)
#pragma unroll
      for (int blk = 0; blk < 4; blk++) {
        float v0 = oacc[dt][blk * 4 + 0] * fA + scr[sbase + dt * 16 + blk * 4 + 0] * fB;
        float v1 = oacc[dt][blk * 4 + 1] * fA + scr[sbase + dt * 16 + blk * 4 + 1] * fB;
        float v2 = oacc[dt][blk * 4 + 2] * fA + scr[sbase + dt * 16 + blk * 4 + 2] * fB;
        float v3 = oacc[dt][blk * 4 + 3] * fA + scr[sbase + dt * 16 + blk * 4 + 3] * fB;
        uint2 st; st.x = pk2(v0, v1); st.y = pk2(v2, v3);
        int d0 = dt * 32 + blk * 8 + 4 * hi;
        *(uint2*)&O[(size_t)qrow * DM + hd * DH + d0] = st;
      }
  }
}

// ---------------------------------------------------------------- launch
extern "C" void kernel_launch(void* const* d_in, const int* in_sizes, int n_in,
                              void* d_out, int out_size, void* d_ws, size_t ws_size,
                              hipStream_t stream) {
  const float* q = (const float*)d_in[0];
  const float* k = (const float*)d_in[1];
  const float* v = (const float*)d_in[2];
  // d_in[3] = mask (causal, reconstructed analytically)
  const float* Wq = (const float*)d_in[4];
  const float* Wk = (const float*)d_in[5];
  const float* Wv = (const float*)d_in[6];
  const float* Wo = (const float*)d_in[7];

  unsigned short* W = (unsigned short*)d_ws;
  const int SM = S_LEN * DM;        // 4194304
  const int WM = DM * DM;           // 1048576
  unsigned short* qb  = W;
  unsigned short* kb  = qb + SM;
  unsigned short* vb  = kb + SM;
  unsigned short* Wqb = vb + SM;
  unsigned short* Wkb = Wqb + WM;
  unsigned short* Wvb = Wkb + WM;
  unsigned short* Wob = Wvb + WM;
  unsigned short* Qh  = Wob + WM;
  unsigned short* Kh  = Qh + SM;
  unsigned short* V4  = Kh + SM;
  unsigned short* Ob  = V4 + SM;

  // 1) casts; Wq carries attention scale in log2 domain: 0.125 * log2(e)
  CastArgs ca;
  ca.src[0] = q;  ca.dst[0] = qb;  ca.n[0] = SM; ca.scl[0] = 1.f;
  ca.src[1] = k;  ca.dst[1] = kb;  ca.n[1] = SM; ca.scl[1] = 1.f;
  ca.src[2] = v;  ca.dst[2] = vb;  ca.n[2] = SM; ca.scl[2] = 1.f;
  ca.src[3] = Wq; ca.dst[3] = Wqb; ca.n[3] = WM; ca.scl[3] = 0.125f * 1.44269504f;
  ca.src[4] = Wk; ca.dst[4] = Wkb; ca.n[4] = WM; ca.scl[4] = 1.f;
  ca.src[5] = Wv; ca.dst[5] = Wvb; ca.n[5] = WM; ca.scl[5] = 1.f;
  ca.src[6] = Wo; ca.dst[6] = Wob; ca.n[6] = WM; ca.scl[6] = 1.f;
  ca.src[7] = Wo; ca.dst[7] = Wob; ca.n[7] = 0;  ca.scl[7] = 1.f;
  cast_all<<<dim3(2048, 8), 256, 0, stream>>>(ca);

  // 2) batched projections: Q->(h,s,d), K->(h,s,d), V->tiles
  ProjArgs pa;
  pa.A[0] = qb; pa.B[0] = Wqb; pa.C[0] = Qh; pa.mode[0] = 1;
  pa.A[1] = kb; pa.B[1] = Wkb; pa.C[1] = Kh; pa.mode[1] = 1;
  pa.A[2] = vb; pa.B[2] = Wvb; pa.C[2] = V4; pa.mode[2] = 2;
  gemm_proj<<<dim3(8, 32, 3), 256, 0, stream>>>(pa);

  // 3) causal flash attention (barrier-free, 2-wave blocks)
  attn_fwd<<<dim3(2048), 128, 0, stream>>>(Qh, Kh, V4, Ob);

  // 4) output projection -> fp32
  gemm_one<<<dim3(8, 32), 256, 0, stream>>>(Ob, Wob, d_out, 0);
}

// Round 6
// 133.492 us; speedup vs baseline: 1.6237x; 1.6237x over previous
//
#include <hip/hip_runtime.h>

// ---------------------------------------------------------------------------
// MultiHeadAttention forward, MI355X (gfx950), bf16 MFMA pipeline.
// Round 6 = best-of rounds 4+5:
//   attn: round-4 structure (kv-split x2, 8 waves, GLL-staged double-buffered
//         K/V in LDS, defer-max, exp2 domain) — proven 72.5 us. Adapted to the
//         V4 tiled layout [h][s/64][d][s%64] so V staging == K staging form.
//         3-ary max nesting to encourage v_max3 fusion.
//   gemm: round-5 (BK=64, row-XOR LDS swizzle, pre-swizzled GLL source) —
//         proven ~17 us faster than round-4 gemm.
// ---------------------------------------------------------------------------

typedef __attribute__((ext_vector_type(8))) short bf16x8;
typedef __attribute__((ext_vector_type(4))) float f32x4;
typedef __attribute__((ext_vector_type(16))) float f32x16;

#define S_LEN 4096
#define DM 1024
#define NH 16
#define DH 64

static __device__ __forceinline__ unsigned short f2bf(float f) {
  union { float f; unsigned u; } x; x.f = f;
  unsigned u = x.u;
  u += 0x7fffu + ((u >> 16) & 1u);   // round-to-nearest-even
  return (unsigned short)(u >> 16);
}

// pack two f32 -> one u32 of two bf16 (RNE), single HW instr on gfx950
static __device__ __forceinline__ unsigned pk2(float lo, float hi) {
  unsigned r;
  asm("v_cvt_pk_bf16_f32 %0, %1, %2" : "=v"(r) : "v"(lo), "v"(hi));
  return r;
}

static __device__ __forceinline__ float exp2_(float x) {
#if __has_builtin(__builtin_amdgcn_exp2f)
  return __builtin_amdgcn_exp2f(x);
#else
  return exp2f(x);
#endif
}

#define GLL16(gsrc, ldst)                                                      \
  __builtin_amdgcn_global_load_lds(                                            \
      (const __attribute__((address_space(1))) void*)(gsrc),                   \
      (__attribute__((address_space(3))) void*)(ldst), 16, 0, 0)

// ---------------------------------------------------------------- cast kernel
struct CastArgs {
  const float* src[8];
  unsigned short* dst[8];
  int n[8];
  float scl[8];
};

__global__ __launch_bounds__(256) void cast_all(CastArgs a) {
  int which = blockIdx.y;
  const float* __restrict__ src = a.src[which];
  unsigned short* __restrict__ dst = a.dst[which];
  int n = a.n[which];
  float s = a.scl[which];
  int i = (blockIdx.x * 256 + threadIdx.x) * 8;
  if (i >= n) return;
  f32x4 v0 = *(const f32x4*)(src + i);
  f32x4 v1 = *(const f32x4*)(src + i + 4);
  union { bf16x8 v; unsigned short u[8]; } o;
#pragma unroll
  for (int j = 0; j < 4; j++) { o.u[j] = f2bf(v0[j] * s); o.u[4 + j] = f2bf(v1[j] * s); }
  *(bf16x8*)(dst + i) = o.v;
}

// ---------------------------------------------------------------- GEMM body
// C[4096][1024] = A[4096][1024] @ B[1024][1024]^T  (bf16; B is N x K)
// 128x128 tile, BK=64, 4 waves x 64x64. LDS tiles [128][64] shorts with
// row-XOR swizzle: element (row, c) lives at row*64 + (c ^ ((row&7)<<3)).
// Staged via global_load_lds with pre-swizzled GLOBAL source (linear LDS dst).
// mode 0: fp32 C[s][n]; mode 1: bf16 (h,s,d); mode 2: bf16 V-tiles
// [h][s/64][d][s%64] (contiguous 8KB per 64-kv tile).
static __device__ __forceinline__ void gemm_body(
    const unsigned short* __restrict__ A, const unsigned short* __restrict__ B,
    void* __restrict__ Cout, int mode, unsigned short* As, unsigned short* Bs) {
  const int K = 1024;
  int tid = threadIdx.x;
  int wid = tid >> 6, lane = tid & 63;
  int m0 = blockIdx.y * 128, n0 = blockIdx.x * 128;
  int wr = (wid >> 1) * 64, wc = (wid & 1) * 64;
  int g = lane >> 4, r = lane & 15;

  const int srow = wid * 8 + (lane >> 3);
  const int scol = 8 * ((lane & 7) ^ ((lane >> 3) & 7));
  const unsigned short* gA[4];
  const unsigned short* gB[4];
#pragma unroll
  for (int rr = 0; rr < 4; rr++) {
    gA[rr] = A + (size_t)(m0 + rr * 32 + srow) * K + scol;
    gB[rr] = B + (size_t)(n0 + rr * 32 + srow) * K + scol;
  }

  f32x4 acc[4][4] = {};
  const int rsw = (r & 7) << 3;   // read-side swizzle (shorts)

  for (int k0 = 0; k0 < K; k0 += 64) {
#pragma unroll
    for (int rr = 0; rr < 4; rr++) {
      GLL16(gA[rr] + k0, As + wid * 512 + rr * 2048);
      GLL16(gB[rr] + k0, Bs + wid * 512 + rr * 2048);
    }
    __syncthreads();

#pragma unroll
    for (int kk = 0; kk < 64; kk += 32) {
      bf16x8 af[4], bfr[4];
#pragma unroll
      for (int mi = 0; mi < 4; mi++)
        af[mi] = *(const bf16x8*)&As[(wr + mi * 16 + r) * 64 + ((kk + g * 8) ^ rsw)];
#pragma unroll
      for (int ni = 0; ni < 4; ni++)
        bfr[ni] = *(const bf16x8*)&Bs[(wc + ni * 16 + r) * 64 + ((kk + g * 8) ^ rsw)];
#pragma unroll
      for (int mi = 0; mi < 4; mi++)
#pragma unroll
        for (int ni = 0; ni < 4; ni++)
          acc[mi][ni] = __builtin_amdgcn_mfma_f32_16x16x32_bf16(
              af[mi], bfr[ni], acc[mi][ni], 0, 0, 0);
    }
    __syncthreads();
  }

  // epilogue: C frag layout col = lane&15, row = (lane>>4)*4 + reg
  if (mode == 0) {
    float* C = (float*)Cout;
#pragma unroll
    for (int mi = 0; mi < 4; mi++) {
      int row = m0 + wr + mi * 16 + g * 4;
#pragma unroll
      for (int ni = 0; ni < 4; ni++) {
        int c = n0 + wc + ni * 16 + r;
#pragma unroll
        for (int j = 0; j < 4; j++)
          C[(size_t)(row + j) * DM + c] = acc[mi][ni][j];
      }
    }
  } else if (mode == 1) {
    unsigned short* Cb = (unsigned short*)Cout;
#pragma unroll
    for (int mi = 0; mi < 4; mi++) {
      int row = m0 + wr + mi * 16 + g * 4;
#pragma unroll
      for (int ni = 0; ni < 4; ni++) {
        int c = n0 + wc + ni * 16 + r;
        int h = c >> 6, d = c & 63;
#pragma unroll
        for (int j = 0; j < 4; j++)
          Cb[(size_t)h * (S_LEN * DH) + (size_t)(row + j) * DH + d] =
              f2bf(acc[mi][ni][j]);
      }
    }
  } else {
    // V tiles: [h][s/64][d][s%64]
    unsigned short* Cb = (unsigned short*)Cout;
#pragma unroll
    for (int mi = 0; mi < 4; mi++) {
      int row = m0 + wr + mi * 16 + g * 4;
#pragma unroll
      for (int ni = 0; ni < 4; ni++) {
        int c = n0 + wc + ni * 16 + r;
        int h = c >> 6, d = c & 63;
#pragma unroll
        for (int j = 0; j < 4; j++) {
          int s = row + j;
          Cb[(size_t)h * (S_LEN * DH) + (size_t)(s >> 6) * 4096 + d * 64 + (s & 63)] =
              f2bf(acc[mi][ni][j]);
        }
      }
    }
  }
}

struct ProjArgs {
  const unsigned short* A[3];
  const unsigned short* B[3];
  unsigned short* C[3];
  int mode[3];
};

__global__ __launch_bounds__(256, 2) void gemm_proj(ProjArgs p) {
  __shared__ unsigned short As[8192];
  __shared__ unsigned short Bs[8192];
  int z = blockIdx.z;
  gemm_body(p.A[z], p.B[z], p.C[z], p.mode[z], As, Bs);
}

__global__ __launch_bounds__(256, 2) void gemm_one(
    const unsigned short* __restrict__ A, const unsigned short* __restrict__ B,
    void* __restrict__ Cout, int mode) {
  __shared__ unsigned short As[8192];
  __shared__ unsigned short Bs[8192];
  gemm_body(A, B, Cout, mode, As, Bs);
}

// ---------------------------------------------------------------- attention
// Round-4 structure: 512 blocks (32 q-supertiles x 16 heads) x 512 threads.
// wave = (gg = kv-half, qi = q-sub-block). K: (h,s,d); V4 tiles
// [h][s/64][d][s%64] => K and V tiles are both contiguous 8KB, same staging.
__global__ __launch_bounds__(512, 4) void attn_fwd(
    const unsigned short* __restrict__ Qh, const unsigned short* __restrict__ Kh,
    const unsigned short* __restrict__ V4, unsigned short* __restrict__ O) {
  __shared__ char smem[65536];   // [gg][db] 16KB {K 8KB, V 8KB}; reused as combine scratch

  const int b = blockIdx.x;
  const int hd = b & 15;
  const int t = b >> 4;
  const int qe = (t < 16) ? (31 - 2 * t) : (2 * (t - 16));  // CU-pairs sum to 31
  const int q0 = qe * 128;
  const int nt = qe + 1;

  const int tid = threadIdx.x;
  const int gg = tid >> 8;            // kv half
  const int ww = (tid >> 6) & 3;      // wave within half-group
  const int lane = tid & 63;
  const int l31 = lane & 31, hi = lane >> 5;
  const int qi = ww;
  const int qw = q0 + qi * 32;
  const int qrow = qw + l31;
  const int sw = (l31 & 7) << 4;

  const unsigned short* Qb = Qh + (size_t)hd * (S_LEN * DH);
  const char* Kb = (const char*)(Kh + (size_t)hd * (S_LEN * DH));
  const char* Vb = (const char*)(V4 + (size_t)hd * (S_LEN * DH));

  // Q fragments (B operand): col = q (l31), k = m*16 + hi*8 + j (pre-scaled)
  bf16x8 qf[4];
#pragma unroll
  for (int m = 0; m < 4; m++)
    qf[m] = *(const bf16x8*)&Qb[(size_t)qrow * DH + m * 16 + hi * 8];

  // staging: waves 0-1 of each group stage K, 2-3 stage V. Both are 8KB
  // contiguous tiles; pre-swizzled global source, linear LDS dest.
  const int roleV = (ww >= 2);
  const int wv = ww & 1;
  const char* gb = roleV ? Vb : Kb;
  int soff[4];
#pragma unroll
  for (int q2 = 0; q2 < 4; q2++) {
    int rowl = wv * 32 + q2 * 8 + (lane >> 3);
    int cb = ((lane & 7) * 16) ^ (((lane >> 3) & 7) << 4);
    soff[q2] = rowl * 128 + cb;
  }
  const int ldsc = gg * 32768 + roleV * 8192 + wv * 4096;  // + db*16384

  f32x16 oacc[2] = {};    // O^T: d = dt*32 + (rg&3)+8*(rg>>2)+4*hi, col q = l31
  float m_r = -1e30f, l_r = 0.f;

  // prologue: stage this group's tile 0 into db=0
  {
    const char* gp = gb + (long)(gg * nt) * 8192;
#pragma unroll
    for (int q2 = 0; q2 < 4; q2++)
      GLL16(gp + soff[q2], smem + ldsc + q2 * 1024);
  }
  __syncthreads();

  int db = 0;
  for (int it = 0; it < nt; ++it) {
    if (it + 1 < nt) {   // prefetch next tile into alternate buffer (async)
      const char* gp = gb + (long)(gg * nt + it + 1) * 8192;
      char* lb = smem + ldsc + (db ^ 1) * 16384;
#pragma unroll
      for (int q2 = 0; q2 < 4; q2++)
        GLL16(gp + soff[q2], lb + q2 * 1024);
    }
    const int kv0 = (gg * nt + it) * 64;
    const char* Kc = smem + gg * 32768 + db * 16384;
    const char* Vc = Kc + 8192;

    if (kv0 <= qw + 31) {                       // wave-uniform causal skip
      const bool hiP = (kv0 + 32 <= qw + 31);   // upper 32-kv sub-tile present
      const bool interior = (kv0 + 63 <= qw);   // no masking anywhere
      // ---- QK^T (swapped): S^T[kv][q], log2 domain
      f32x16 s0 = {}, s1 = {};
#pragma unroll
      for (int m = 0; m < 4; m++) {
        bf16x8 kf = *(const bf16x8*)(Kc + l31 * 128 + ((m * 32 + hi * 16) ^ sw));
        s0 = __builtin_amdgcn_mfma_f32_32x32x16_bf16(kf, qf[m], s0, 0, 0, 0);
      }
      if (hiP) {
#pragma unroll
        for (int m = 0; m < 4; m++) {
          bf16x8 kf = *(const bf16x8*)(Kc + (32 + l31) * 128 + ((m * 32 + hi * 16) ^ sw));
          s1 = __builtin_amdgcn_mfma_f32_32x32x16_bf16(kf, qf[m], s1, 0, 0, 0);
        }
      }
      // ---- causal mask: diagonal tiles only (reg -> kv: (rg&3)+8*(rg>>2)+4*hi)
      if (!interior) {
#pragma unroll
        for (int rg = 0; rg < 16; rg++) {
          const int kvl = (rg & 3) + 8 * (rg >> 2) + 4 * hi;
          s0[rg] = (kv0 + kvl <= qrow) ? s0[rg] : -1e30f;
          s1[rg] = (hiP && kv0 + 32 + kvl <= qrow) ? s1[rg] : -1e30f;
        }
      }
      // ---- max: 3-ary tree (v_max3 fusion) + shfl_xor(32) cross-half
      float t0 = fmaxf(fmaxf(s0[0], s0[1]), s0[2]);
      float t1 = fmaxf(fmaxf(s0[3], s0[4]), s0[5]);
      float t2 = fmaxf(fmaxf(s0[6], s0[7]), s0[8]);
      float t3 = fmaxf(fmaxf(s0[9], s0[10]), s0[11]);
      float t4 = fmaxf(fmaxf(s0[12], s0[13]), s0[14]);
      float t5 = fmaxf(fmaxf(s0[15], s1[0]), s1[1]);
      float t6 = fmaxf(fmaxf(s1[2], s1[3]), s1[4]);
      float t7 = fmaxf(fmaxf(s1[5], s1[6]), s1[7]);
      float t8 = fmaxf(fmaxf(s1[8], s1[9]), s1[10]);
      float t9 = fmaxf(fmaxf(s1[11], s1[12]), s1[13]);
      float ta = fmaxf(s1[14], s1[15]);
      float u0 = fmaxf(fmaxf(t0, t1), t2);
      float u1 = fmaxf(fmaxf(t3, t4), t5);
      float u2 = fmaxf(fmaxf(t6, t7), t8);
      float u3 = fmaxf(t9, ta);
      float mx = fmaxf(fmaxf(u0, u1), fmaxf(u2, u3));
      mx = fmaxf(mx, __shfl_xor(mx, 32, 64));
      // ---- defer-max (T13): rescale only when max grew past THR
      if (__any(mx > m_r + 10.0f)) {
        float mnew = fmaxf(m_r, mx);
        float sc = exp2_(m_r - mnew);
        m_r = mnew;
        l_r *= sc;
#pragma unroll
        for (int dt = 0; dt < 2; dt++)
#pragma unroll
          for (int rg = 0; rg < 16; rg++) oacc[dt][rg] *= sc;
      }
      // ---- P = exp2(S - m) in place
#pragma unroll
      for (int rg = 0; rg < 16; rg++) {
        s0[rg] = exp2_(s0[rg] - m_r);
        s1[rg] = exp2_(s1[rg] - m_r);
      }
      // ---- row-sum (parallel quads) + shfl_xor(32) cross-half
      float r0 = (s0[0] + s0[1]) + (s0[2] + s0[3]);
      float r1 = (s0[4] + s0[5]) + (s0[6] + s0[7]);
      float r2 = (s0[8] + s0[9]) + (s0[10] + s0[11]);
      float r3 = (s0[12] + s0[13]) + (s0[14] + s0[15]);
      float r4 = (s1[0] + s1[1]) + (s1[2] + s1[3]);
      float r5 = (s1[4] + s1[5]) + (s1[6] + s1[7]);
      float r6 = (s1[8] + s1[9]) + (s1[10] + s1[11]);
      float r7 = (s1[12] + s1[13]) + (s1[14] + s1[15]);
      float rs = ((r0 + r1) + (r2 + r3)) + ((r4 + r5) + (r6 + r7));
      rs += __shfl_xor(rs, 32, 64);
      l_r += rs;
      // ---- P -> bf16 frags via cvt_pk + shfl_xor(32); PV: O^T += V^T x P
#pragma unroll
      for (int c = 0; c < 2; c++) {
        if (c == 0 || hiP) {
          const f32x16 P = c ? s1 : s0;
          uint2 pk[4], pp[4];
#pragma unroll
          for (int blk = 0; blk < 4; blk++) {
            pk[blk].x = pk2(P[blk * 4 + 0], P[blk * 4 + 1]);
            pk[blk].y = pk2(P[blk * 4 + 2], P[blk * 4 + 3]);
            pp[blk].x = (unsigned)__shfl_xor((int)pk[blk].x, 32, 64);
            pp[blk].y = (unsigned)__shfl_xor((int)pk[blk].y, 32, 64);
          }
#pragma unroll
          for (int n = 0; n < 2; n++) {
            union { unsigned w[4]; bf16x8 v; } u;
            u.w[0] = hi ? pp[2 * n + 1].x : pk[2 * n].x;
            u.w[1] = hi ? pp[2 * n + 1].y : pk[2 * n].y;
            u.w[2] = hi ? pk[2 * n + 1].x : pp[2 * n].x;
            u.w[3] = hi ? pk[2 * n + 1].y : pp[2 * n].y;
#pragma unroll
            for (int dt = 0; dt < 2; dt++) {
              bf16x8 vf = *(const bf16x8*)(Vc + (dt * 32 + l31) * 128 +
                            ((c * 64 + n * 32 + hi * 16) ^ sw));
              oacc[dt] = __builtin_amdgcn_mfma_f32_32x32x16_bf16(
                  vf, u.v, oacc[dt], 0, 0, 0);
            }
          }
        }
      }
    }
    __syncthreads();
    db ^= 1;
  }

  // ---- combine halves via LDS scratch (stride 35 floats: conflict-free)
  float* scr = (float*)smem;
  const int sbase = (qi * 64 + lane) * 35;
  if (gg == 1) {
#pragma unroll
    for (int dt = 0; dt < 2; dt++)
#pragma unroll
      for (int rg = 0; rg < 16; rg++) scr[sbase + dt * 16 + rg] = oacc[dt][rg];
    scr[sbase + 32] = m_r;
    scr[sbase + 33] = l_r;
  }
  __syncthreads();
  if (gg == 0) {
    float mB = scr[sbase + 32], lB = scr[sbase + 33];
    float mS = fmaxf(m_r, mB);
    float sA = exp2_(m_r - mS);
    float sB = exp2_(mB - mS);
    float rl = 1.0f / (l_r * sA + lB * sB);
    float fA = sA * rl, fB = sB * rl;
#pragma unroll
    for (int dt = 0; dt < 2; dt++)
#pragma unroll
      for (int blk = 0; blk < 4; blk++) {
        float v0 = oacc[dt][blk * 4 + 0] * fA + scr[sbase + dt * 16 + blk * 4 + 0] * fB;
        float v1 = oacc[dt][blk * 4 + 1] * fA + scr[sbase + dt * 16 + blk * 4 + 1] * fB;
        float v2 = oacc[dt][blk * 4 + 2] * fA + scr[sbase + dt * 16 + blk * 4 + 2] * fB;
        float v3 = oacc[dt][blk * 4 + 3] * fA + scr[sbase + dt * 16 + blk * 4 + 3] * fB;
        uint2 st; st.x = pk2(v0, v1); st.y = pk2(v2, v3);
        int d0 = dt * 32 + blk * 8 + 4 * hi;
        *(uint2*)&O[(size_t)qrow * DM + hd * DH + d0] = st;
      }
  }
}

// ---------------------------------------------------------------- launch
extern "C" void kernel_launch(void* const* d_in, const int* in_sizes, int n_in,
                              void* d_out, int out_size, void* d_ws, size_t ws_size,
                              hipStream_t stream) {
  const float* q = (const float*)d_in[0];
  const float* k = (const float*)d_in[1];
  const float* v = (const float*)d_in[2];
  // d_in[3] = mask (causal, reconstructed analytically)
  const float* Wq = (const float*)d_in[4];
  const float* Wk = (const float*)d_in[5];
  const float* Wv = (const float*)d_in[6];
  const float* Wo = (const float*)d_in[7];

  unsigned short* W = (unsigned short*)d_ws;
  const int SM = S_LEN * DM;        // 4194304
  const int WM = DM * DM;           // 1048576
  unsigned short* qb  = W;
  unsigned short* kb  = qb + SM;
  unsigned short* vb  = kb + SM;
  unsigned short* Wqb = vb + SM;
  unsigned short* Wkb = Wqb + WM;
  unsigned short* Wvb = Wkb + WM;
  unsigned short* Wob = Wvb + WM;
  unsigned short* Qh  = Wob + WM;
  unsigned short* Kh  = Qh + SM;
  unsigned short* V4  = Kh + SM;
  unsigned short* Ob  = V4 + SM;

  // 1) casts; Wq carries attention scale in log2 domain: 0.125 * log2(e)
  CastArgs ca;
  ca.src[0] = q;  ca.dst[0] = qb;  ca.n[0] = SM; ca.scl[0] = 1.f;
  ca.src[1] = k;  ca.dst[1] = kb;  ca.n[1] = SM; ca.scl[1] = 1.f;
  ca.src[2] = v;  ca.dst[2] = vb;  ca.n[2] = SM; ca.scl[2] = 1.f;
  ca.src[3] = Wq; ca.dst[3] = Wqb; ca.n[3] = WM; ca.scl[3] = 0.125f * 1.44269504f;
  ca.src[4] = Wk; ca.dst[4] = Wkb; ca.n[4] = WM; ca.scl[4] = 1.f;
  ca.src[5] = Wv; ca.dst[5] = Wvb; ca.n[5] = WM; ca.scl[5] = 1.f;
  ca.src[6] = Wo; ca.dst[6] = Wob; ca.n[6] = WM; ca.scl[6] = 1.f;
  ca.src[7] = Wo; ca.dst[7] = Wob; ca.n[7] = 0;  ca.scl[7] = 1.f;
  cast_all<<<dim3(2048, 8), 256, 0, stream>>>(ca);

  // 2) batched projections: Q->(h,s,d), K->(h,s,d), V->tiles
  ProjArgs pa;
  pa.A[0] = qb; pa.B[0] = Wqb; pa.C[0] = Qh; pa.mode[0] = 1;
  pa.A[1] = kb; pa.B[1] = Wkb; pa.C[1] = Kh; pa.mode[1] = 1;
  pa.A[2] = vb; pa.B[2] = Wvb; pa.C[2] = V4; pa.mode[2] = 2;
  gemm_proj<<<dim3(8, 32, 3), 256, 0, stream>>>(pa);

  // 3) causal flash attention (kv-split x2, 8 waves/block, GLL-staged)
  attn_fwd<<<dim3(512), 512, 0, stream>>>(Qh, Kh, V4, Ob);

  // 4) output projection -> fp32
  gemm_one<<<dim3(8, 32), 256, 0, stream>>>(Ob, Wob, d_out, 0);
}

// Round 7
// 125.626 us; speedup vs baseline: 1.7254x; 1.0626x over previous
//
#include <hip/hip_runtime.h>

// ---------------------------------------------------------------------------
// MultiHeadAttention forward, MI355X (gfx950), bf16 MFMA pipeline.
// Round 7 = round 6 with attention serial-chain cuts (GEMM/cast untouched):
//   - speculative exp2 with m_init=16: exp issues right after mask; deferred
//     p-domain overflow check (__any(max_p > 2^10)) with multiplicative fixup.
//     Fast path has ZERO cross-lane softmax ops; l cross-half-summed once at end.
//   - P-exchange via v_permlane32_swap_b32 (element-wise vdst[32+i]<->vsrc[i]),
//     derived equivalent to the proven round-6 shfl construction: no selects.
//   - c=0 V-fragment ds_reads hoisted before softmax (latency off PV chain).
// ---------------------------------------------------------------------------

typedef __attribute__((ext_vector_type(8))) short bf16x8;
typedef __attribute__((ext_vector_type(4))) float f32x4;
typedef __attribute__((ext_vector_type(16))) float f32x16;

#define S_LEN 4096
#define DM 1024
#define NH 16
#define DH 64

static __device__ __forceinline__ unsigned short f2bf(float f) {
  union { float f; unsigned u; } x; x.f = f;
  unsigned u = x.u;
  u += 0x7fffu + ((u >> 16) & 1u);   // round-to-nearest-even
  return (unsigned short)(u >> 16);
}

// pack two f32 -> one u32 of two bf16 (RNE), single HW instr on gfx950
static __device__ __forceinline__ unsigned pk2(float lo, float hi) {
  unsigned r;
  asm("v_cvt_pk_bf16_f32 %0, %1, %2" : "=v"(r) : "v"(lo), "v"(hi));
  return r;
}

// gfx950: element-wise half-wave exchange: vdst[32+i] <-> vsrc[i], i=0..31.
// After swap(a,b): lanes<32 keep a, get partner-lo data in b;
//                  lanes>=32 get partner-hi data in a, keep b.
static __device__ __forceinline__ void swap32u(unsigned& a, unsigned& b) {
  asm("v_permlane32_swap_b32 %0, %1" : "+v"(a), "+v"(b));
}

static __device__ __forceinline__ float exp2_(float x) {
#if __has_builtin(__builtin_amdgcn_exp2f)
  return __builtin_amdgcn_exp2f(x);
#else
  return exp2f(x);
#endif
}

#define GLL16(gsrc, ldst)                                                      \
  __builtin_amdgcn_global_load_lds(                                            \
      (const __attribute__((address_space(1))) void*)(gsrc),                   \
      (__attribute__((address_space(3))) void*)(ldst), 16, 0, 0)

// ---------------------------------------------------------------- cast kernel
struct CastArgs {
  const float* src[8];
  unsigned short* dst[8];
  int n[8];
  float scl[8];
};

__global__ __launch_bounds__(256) void cast_all(CastArgs a) {
  int which = blockIdx.y;
  const float* __restrict__ src = a.src[which];
  unsigned short* __restrict__ dst = a.dst[which];
  int n = a.n[which];
  float s = a.scl[which];
  int i = (blockIdx.x * 256 + threadIdx.x) * 8;
  if (i >= n) return;
  f32x4 v0 = *(const f32x4*)(src + i);
  f32x4 v1 = *(const f32x4*)(src + i + 4);
  union { bf16x8 v; unsigned short u[8]; } o;
#pragma unroll
  for (int j = 0; j < 4; j++) { o.u[j] = f2bf(v0[j] * s); o.u[4 + j] = f2bf(v1[j] * s); }
  *(bf16x8*)(dst + i) = o.v;
}

// ---------------------------------------------------------------- GEMM body
// (unchanged from round 6 -- verified)
static __device__ __forceinline__ void gemm_body(
    const unsigned short* __restrict__ A, const unsigned short* __restrict__ B,
    void* __restrict__ Cout, int mode, unsigned short* As, unsigned short* Bs) {
  const int K = 1024;
  int tid = threadIdx.x;
  int wid = tid >> 6, lane = tid & 63;
  int m0 = blockIdx.y * 128, n0 = blockIdx.x * 128;
  int wr = (wid >> 1) * 64, wc = (wid & 1) * 64;
  int g = lane >> 4, r = lane & 15;

  const int srow = wid * 8 + (lane >> 3);
  const int scol = 8 * ((lane & 7) ^ ((lane >> 3) & 7));
  const unsigned short* gA[4];
  const unsigned short* gB[4];
#pragma unroll
  for (int rr = 0; rr < 4; rr++) {
    gA[rr] = A + (size_t)(m0 + rr * 32 + srow) * K + scol;
    gB[rr] = B + (size_t)(n0 + rr * 32 + srow) * K + scol;
  }

  f32x4 acc[4][4] = {};
  const int rsw = (r & 7) << 3;   // read-side swizzle (shorts)

  for (int k0 = 0; k0 < K; k0 += 64) {
#pragma unroll
    for (int rr = 0; rr < 4; rr++) {
      GLL16(gA[rr] + k0, As + wid * 512 + rr * 2048);
      GLL16(gB[rr] + k0, Bs + wid * 512 + rr * 2048);
    }
    __syncthreads();

#pragma unroll
    for (int kk = 0; kk < 64; kk += 32) {
      bf16x8 af[4], bfr[4];
#pragma unroll
      for (int mi = 0; mi < 4; mi++)
        af[mi] = *(const bf16x8*)&As[(wr + mi * 16 + r) * 64 + ((kk + g * 8) ^ rsw)];
#pragma unroll
      for (int ni = 0; ni < 4; ni++)
        bfr[ni] = *(const bf16x8*)&Bs[(wc + ni * 16 + r) * 64 + ((kk + g * 8) ^ rsw)];
#pragma unroll
      for (int mi = 0; mi < 4; mi++)
#pragma unroll
        for (int ni = 0; ni < 4; ni++)
          acc[mi][ni] = __builtin_amdgcn_mfma_f32_16x16x32_bf16(
              af[mi], bfr[ni], acc[mi][ni], 0, 0, 0);
    }
    __syncthreads();
  }

  if (mode == 0) {
    float* C = (float*)Cout;
#pragma unroll
    for (int mi = 0; mi < 4; mi++) {
      int row = m0 + wr + mi * 16 + g * 4;
#pragma unroll
      for (int ni = 0; ni < 4; ni++) {
        int c = n0 + wc + ni * 16 + r;
#pragma unroll
        for (int j = 0; j < 4; j++)
          C[(size_t)(row + j) * DM + c] = acc[mi][ni][j];
      }
    }
  } else if (mode == 1) {
    unsigned short* Cb = (unsigned short*)Cout;
#pragma unroll
    for (int mi = 0; mi < 4; mi++) {
      int row = m0 + wr + mi * 16 + g * 4;
#pragma unroll
      for (int ni = 0; ni < 4; ni++) {
        int c = n0 + wc + ni * 16 + r;
        int h = c >> 6, d = c & 63;
#pragma unroll
        for (int j = 0; j < 4; j++)
          Cb[(size_t)h * (S_LEN * DH) + (size_t)(row + j) * DH + d] =
              f2bf(acc[mi][ni][j]);
      }
    }
  } else {
    // V tiles: [h][s/64][d][s%64]
    unsigned short* Cb = (unsigned short*)Cout;
#pragma unroll
    for (int mi = 0; mi < 4; mi++) {
      int row = m0 + wr + mi * 16 + g * 4;
#pragma unroll
      for (int ni = 0; ni < 4; ni++) {
        int c = n0 + wc + ni * 16 + r;
        int h = c >> 6, d = c & 63;
#pragma unroll
        for (int j = 0; j < 4; j++) {
          int s = row + j;
          Cb[(size_t)h * (S_LEN * DH) + (size_t)(s >> 6) * 4096 + d * 64 + (s & 63)] =
              f2bf(acc[mi][ni][j]);
        }
      }
    }
  }
}

struct ProjArgs {
  const unsigned short* A[3];
  const unsigned short* B[3];
  unsigned short* C[3];
  int mode[3];
};

__global__ __launch_bounds__(256, 2) void gemm_proj(ProjArgs p) {
  __shared__ unsigned short As[8192];
  __shared__ unsigned short Bs[8192];
  int z = blockIdx.z;
  gemm_body(p.A[z], p.B[z], p.C[z], p.mode[z], As, Bs);
}

__global__ __launch_bounds__(256, 2) void gemm_one(
    const unsigned short* __restrict__ A, const unsigned short* __restrict__ B,
    void* __restrict__ Cout, int mode) {
  __shared__ unsigned short As[8192];
  __shared__ unsigned short Bs[8192];
  gemm_body(A, B, Cout, mode, As, Bs);
}

// ---------------------------------------------------------------- attention
// 512 blocks (32 q-supertiles x 16 heads) x 512 threads (8 waves).
// wave = (gg = kv-half, qi = q-sub-block). K: (h,s,d); V4 tiles
// [h][s/64][d][s%64]. GLL-staged double-buffered LDS (round-6 proven).
__global__ __launch_bounds__(512, 4) void attn_fwd(
    const unsigned short* __restrict__ Qh, const unsigned short* __restrict__ Kh,
    const unsigned short* __restrict__ V4, unsigned short* __restrict__ O) {
  __shared__ char smem[65536];   // [gg][db] 16KB {K 8KB, V 8KB}; reused as combine scratch

  const int b = blockIdx.x;
  const int hd = b & 15;
  const int t = b >> 4;
  const int qe = (t < 16) ? (31 - 2 * t) : (2 * (t - 16));  // CU-pairs sum to 31
  const int q0 = qe * 128;
  const int nt = qe + 1;

  const int tid = threadIdx.x;
  const int gg = tid >> 8;            // kv half
  const int ww = (tid >> 6) & 3;      // wave within half-group
  const int lane = tid & 63;
  const int l31 = lane & 31, hi = lane >> 5;
  const int qi = ww;
  const int qw = q0 + qi * 32;
  const int qrow = qw + l31;
  const int sw = (l31 & 7) << 4;

  const unsigned short* Qb = Qh + (size_t)hd * (S_LEN * DH);
  const char* Kb = (const char*)(Kh + (size_t)hd * (S_LEN * DH));
  const char* Vb = (const char*)(V4 + (size_t)hd * (S_LEN * DH));

  // Q fragments (B operand): col = q (l31), k = m*16 + hi*8 + j (pre-scaled)
  bf16x8 qf[4];
#pragma unroll
  for (int m = 0; m < 4; m++)
    qf[m] = *(const bf16x8*)&Qb[(size_t)qrow * DH + m * 16 + hi * 8];

  // staging: waves 0-1 of each group stage K, 2-3 stage V (8KB tiles each).
  const int roleV = (ww >= 2);
  const int wv = ww & 1;
  const char* gb = roleV ? Vb : Kb;
  int soff[4];
#pragma unroll
  for (int q2 = 0; q2 < 4; q2++) {
    int rowl = wv * 32 + q2 * 8 + (lane >> 3);
    int cb = ((lane & 7) * 16) ^ (((lane >> 3) & 7) << 4);
    soff[q2] = rowl * 128 + cb;
  }
  const int ldsc = gg * 32768 + roleV * 8192 + wv * 4096;  // + db*16384

  f32x16 oacc[2] = {};    // O^T: d = dt*32 + (rg&3)+8*(rg>>2)+4*hi, col q = l31
  // Speculative-exp baseline: m_r = 16 (scores never approach 26, so the
  // overflow fixup below virtually never fires; ratios are scale-invariant).
  float m_r = 16.0f, l_r = 0.f;   // l_r = OWN-HALF partial sum until the end

  // prologue: stage this group's tile 0 into db=0
  {
    const char* gp = gb + (long)(gg * nt) * 8192;
#pragma unroll
    for (int q2 = 0; q2 < 4; q2++)
      GLL16(gp + soff[q2], smem + ldsc + q2 * 1024);
  }
  __syncthreads();

  int db = 0;
  for (int it = 0; it < nt; ++it) {
    if (it + 1 < nt) {   // prefetch next tile into alternate buffer (async)
      const char* gp = gb + (long)(gg * nt + it + 1) * 8192;
      char* lb = smem + ldsc + (db ^ 1) * 16384;
#pragma unroll
      for (int q2 = 0; q2 < 4; q2++)
        GLL16(gp + soff[q2], lb + q2 * 1024);
    }
    const int kv0 = (gg * nt + it) * 64;
    const char* Kc = smem + gg * 32768 + db * 16384;
    const char* Vc = Kc + 8192;

    if (kv0 <= qw + 31) {                       // wave-uniform causal skip
      const bool hiP = (kv0 + 32 <= qw + 31);   // upper 32-kv sub-tile present
      const bool interior = (kv0 + 63 <= qw);   // no masking anywhere
      // ---- QK^T (swapped): S^T[kv][q], log2 domain
      f32x16 s0 = {}, s1 = {};
#pragma unroll
      for (int m = 0; m < 4; m++) {
        bf16x8 kf = *(const bf16x8*)(Kc + l31 * 128 + ((m * 32 + hi * 16) ^ sw));
        s0 = __builtin_amdgcn_mfma_f32_32x32x16_bf16(kf, qf[m], s0, 0, 0, 0);
      }
      if (hiP) {
#pragma unroll
        for (int m = 0; m < 4; m++) {
          bf16x8 kf = *(const bf16x8*)(Kc + (32 + l31) * 128 + ((m * 32 + hi * 16) ^ sw));
          s1 = __builtin_amdgcn_mfma_f32_32x32x16_bf16(kf, qf[m], s1, 0, 0, 0);
        }
      }
      // ---- hoist c=0 V-frag LDS reads (independent of softmax)
      bf16x8 vf0[4];
#pragma unroll
      for (int i = 0; i < 4; i++) {
        const int dt = i >> 1, n = i & 1;
        vf0[i] = *(const bf16x8*)(Vc + (dt * 32 + l31) * 128 +
                   ((n * 32 + hi * 16) ^ sw));
      }
      // ---- causal mask: diagonal tiles only (reg -> kv: (rg&3)+8*(rg>>2)+4*hi)
      if (!interior) {
#pragma unroll
        for (int rg = 0; rg < 16; rg++) {
          const int kvl = (rg & 3) + 8 * (rg >> 2) + 4 * hi;
          s0[rg] = (kv0 + kvl <= qrow) ? s0[rg] : -1e30f;
          s1[rg] = (hiP && kv0 + 32 + kvl <= qrow) ? s1[rg] : -1e30f;
        }
      }
      // ---- P = exp2(S - m) IMMEDIATELY (no wait on any max reduce)
#pragma unroll
      for (int rg = 0; rg < 16; rg++) {
        s0[rg] = exp2_(s0[rg] - m_r);
        s1[rg] = exp2_(s1[rg] - m_r);
      }
      // ---- deferred overflow check in p-domain (off critical path; ~never fires)
      float t0 = fmaxf(fmaxf(s0[0], s0[1]), s0[2]);
      float t1 = fmaxf(fmaxf(s0[3], s0[4]), s0[5]);
      float t2 = fmaxf(fmaxf(s0[6], s0[7]), s0[8]);
      float t3 = fmaxf(fmaxf(s0[9], s0[10]), s0[11]);
      float t4 = fmaxf(fmaxf(s0[12], s0[13]), s0[14]);
      float t5 = fmaxf(fmaxf(s0[15], s1[0]), s1[1]);
      float t6 = fmaxf(fmaxf(s1[2], s1[3]), s1[4]);
      float t7 = fmaxf(fmaxf(s1[5], s1[6]), s1[7]);
      float t8 = fmaxf(fmaxf(s1[8], s1[9]), s1[10]);
      float t9 = fmaxf(fmaxf(s1[11], s1[12]), s1[13]);
      float ta = fmaxf(s1[14], s1[15]);
      float u0 = fmaxf(fmaxf(t0, t1), t2);
      float u1 = fmaxf(fmaxf(t3, t4), t5);
      float u2 = fmaxf(fmaxf(t6, t7), t8);
      float u3 = fmaxf(t9, ta);
      float mxp = fmaxf(fmaxf(u0, u1), fmaxf(u2, u3));
      if (__any(mxp > 1024.0f)) {   // rare: renormalize multiplicatively
        float mrow = fmaxf(mxp, __shfl_xor(mxp, 32, 64));
        float sc = 1.0f / mrow;     // identical across the hi-pair of a q-row
        m_r += __log2f(mrow);
        l_r *= sc;
#pragma unroll
        for (int rg = 0; rg < 16; rg++) { s0[rg] *= sc; s1[rg] *= sc; }
#pragma unroll
        for (int dt = 0; dt < 2; dt++)
#pragma unroll
          for (int rg = 0; rg < 16; rg++) oacc[dt][rg] *= sc;
      }
      // ---- own-half row-sum (cross-half deferred to the end)
      float r0 = (s0[0] + s0[1]) + (s0[2] + s0[3]);
      float r1 = (s0[4] + s0[5]) + (s0[6] + s0[7]);
      float r2 = (s0[8] + s0[9]) + (s0[10] + s0[11]);
      float r3 = (s0[12] + s0[13]) + (s0[14] + s0[15]);
      float r4 = (s1[0] + s1[1]) + (s1[2] + s1[3]);
      float r5 = (s1[4] + s1[5]) + (s1[6] + s1[7]);
      float r6 = (s1[8] + s1[9]) + (s1[10] + s1[11]);
      float r7 = (s1[12] + s1[13]) + (s1[14] + s1[15]);
      l_r += ((r0 + r1) + (r2 + r3)) + ((r4 + r5) + (r6 + r7));
      // ---- P -> bf16 frags via cvt_pk + permlane32_swap (no selects);
      //      mapping verified equivalent to the round-6 shfl construction.
#pragma unroll
      for (int c = 0; c < 2; c++) {
        if (c == 0 || hiP) {
          const f32x16 P = c ? s1 : s0;
#pragma unroll
          for (int n = 0; n < 2; n++) {
            unsigned a0 = pk2(P[8 * n + 0], P[8 * n + 1]);
            unsigned a1 = pk2(P[8 * n + 2], P[8 * n + 3]);
            unsigned b0 = pk2(P[8 * n + 4], P[8 * n + 5]);
            unsigned b1 = pk2(P[8 * n + 6], P[8 * n + 7]);
            swap32u(a0, b0);
            swap32u(a1, b1);
            union { unsigned w[4]; bf16x8 v; } u;
            u.w[0] = a0; u.w[1] = a1; u.w[2] = b0; u.w[3] = b1;
#pragma unroll
            for (int dt = 0; dt < 2; dt++) {
              bf16x8 vf = (c == 0) ? vf0[dt * 2 + n]
                        : *(const bf16x8*)(Vc + (dt * 32 + l31) * 128 +
                             ((64 + n * 32 + hi * 16) ^ sw));
              oacc[dt] = __builtin_amdgcn_mfma_f32_32x32x16_bf16(
                  vf, u.v, oacc[dt], 0, 0, 0);
            }
          }
        }
      }
    }
    __syncthreads();
    db ^= 1;
  }

  // complete the row sum across halves (single deferred shuffle)
  l_r += __shfl_xor(l_r, 32, 64);

  // ---- combine gg-halves via LDS scratch (stride 35 floats: conflict-free)
  float* scr = (float*)smem;
  const int sbase = (qi * 64 + lane) * 35;
  if (gg == 1) {
#pragma unroll
    for (int dt = 0; dt < 2; dt++)
#pragma unroll
      for (int rg = 0; rg < 16; rg++) scr[sbase + dt * 16 + rg] = oacc[dt][rg];
    scr[sbase + 32] = m_r;
    scr[sbase + 33] = l_r;
  }
  __syncthreads();
  if (gg == 0) {
    float mB = scr[sbase + 32], lB = scr[sbase + 33];
    float mS = fmaxf(m_r, mB);
    float sA = exp2_(m_r - mS);
    float sB = exp2_(mB - mS);
    float rl = 1.0f / (l_r * sA + lB * sB);
    float fA = sA * rl, fB = sB * rl;
#pragma unroll
    for (int dt = 0; dt < 2; dt++)
#pragma unroll
      for (int blk = 0; blk < 4; blk++) {
        float v0 = oacc[dt][blk * 4 + 0] * fA + scr[sbase + dt * 16 + blk * 4 + 0] * fB;
        float v1 = oacc[dt][blk * 4 + 1] * fA + scr[sbase + dt * 16 + blk * 4 + 1] * fB;
        float v2 = oacc[dt][blk * 4 + 2] * fA + scr[sbase + dt * 16 + blk * 4 + 2] * fB;
        float v3 = oacc[dt][blk * 4 + 3] * fA + scr[sbase + dt * 16 + blk * 4 + 3] * fB;
        uint2 st; st.x = pk2(v0, v1); st.y = pk2(v2, v3);
        int d0 = dt * 32 + blk * 8 + 4 * hi;
        *(uint2*)&O[(size_t)qrow * DM + hd * DH + d0] = st;
      }
  }
}

// ---------------------------------------------------------------- launch
extern "C" void kernel_launch(void* const* d_in, const int* in_sizes, int n_in,
                              void* d_out, int out_size, void* d_ws, size_t ws_size,
                              hipStream_t stream) {
  const float* q = (const float*)d_in[0];
  const float* k = (const float*)d_in[1];
  const float* v = (const float*)d_in[2];
  // d_in[3] = mask (causal, reconstructed analytically)
  const float* Wq = (const float*)d_in[4];
  const float* Wk = (const float*)d_in[5];
  const float* Wv = (const float*)d_in[6];
  const float* Wo = (const float*)d_in[7];

  unsigned short* W = (unsigned short*)d_ws;
  const int SM = S_LEN * DM;        // 4194304
  const int WM = DM * DM;           // 1048576
  unsigned short* qb  = W;
  unsigned short* kb  = qb + SM;
  unsigned short* vb  = kb + SM;
  unsigned short* Wqb = vb + SM;
  unsigned short* Wkb = Wqb + WM;
  unsigned short* Wvb = Wkb + WM;
  unsigned short* Wob = Wvb + WM;
  unsigned short* Qh  = Wob + WM;
  unsigned short* Kh  = Qh + SM;
  unsigned short* V4  = Kh + SM;
  unsigned short* Ob  = V4 + SM;

  // 1) casts; Wq carries attention scale in log2 domain: 0.125 * log2(e)
  CastArgs ca;
  ca.src[0] = q;  ca.dst[0] = qb;  ca.n[0] = SM; ca.scl[0] = 1.f;
  ca.src[1] = k;  ca.dst[1] = kb;  ca.n[1] = SM; ca.scl[1] = 1.f;
  ca.src[2] = v;  ca.dst[2] = vb;  ca.n[2] = SM; ca.scl[2] = 1.f;
  ca.src[3] = Wq; ca.dst[3] = Wqb; ca.n[3] = WM; ca.scl[3] = 0.125f * 1.44269504f;
  ca.src[4] = Wk; ca.dst[4] = Wkb; ca.n[4] = WM; ca.scl[4] = 1.f;
  ca.src[5] = Wv; ca.dst[5] = Wvb; ca.n[5] = WM; ca.scl[5] = 1.f;
  ca.src[6] = Wo; ca.dst[6] = Wob; ca.n[6] = WM; ca.scl[6] = 1.f;
  ca.src[7] = Wo; ca.dst[7] = Wob; ca.n[7] = 0;  ca.scl[7] = 1.f;
  cast_all<<<dim3(2048, 8), 256, 0, stream>>>(ca);

  // 2) batched projections: Q->(h,s,d), K->(h,s,d), V->tiles
  ProjArgs pa;
  pa.A[0] = qb; pa.B[0] = Wqb; pa.C[0] = Qh; pa.mode[0] = 1;
  pa.A[1] = kb; pa.B[1] = Wkb; pa.C[1] = Kh; pa.mode[1] = 1;
  pa.A[2] = vb; pa.B[2] = Wvb; pa.C[2] = V4; pa.mode[2] = 2;
  gemm_proj<<<dim3(8, 32, 3), 256, 0, stream>>>(pa);

  // 3) causal flash attention (kv-split x2, 8 waves/block, GLL-staged)
  attn_fwd<<<dim3(512), 512, 0, stream>>>(Qh, Kh, V4, Ob);

  // 4) output projection -> fp32
  gemm_one<<<dim3(8, 32), 256, 0, stream>>>(Ob, Wob, d_out, 0);
}